// Round 5
// baseline (218.990 us; speedup 1.0000x reference)
//
#include <hip/hip_runtime.h>
#include <hip/hip_bf16.h>

// EoMT criterion v4: MFMA mask reductions with contention-free partial-sum
// stores (no global atomics) + k_reduce, + fused cost/Hungarian/losses.
// Shapes fixed: bs=2, N=100, C+1=7, H=W=512 (HW=262144), M=20.

typedef unsigned int u32;
typedef __attribute__((ext_vector_type(8))) short short8;   // 8 bf16 (4 VGPRs)
typedef __attribute__((ext_vector_type(4))) float f32x4;

#define BS 2
#define NQ 100
#define C1 7
#define HWPX 262144
#define MG 20
#define NO_OBJ_C 6
#define NROWS 112            // 7 tiles of 16: rows 0-99 real, 100-111 = ones rows (row100 -> ysum)
#define NT 7
#define CHUNK 2048           // pixels per block
#define NCHUNK (HWPX / CHUNK)   // 128
#define NSUB (NCHUNK * 4)    // 512 per-wave sub-chunks
#define WSUB (CHUNK / 4)     // 512 px per wave
#define KSTEPS (WSUB / 32)   // 16

// ---- workspace layout (bytes) ----
static constexpr size_t OFF_PACKED = 0;                                   // u32 [BS][HWPX] = 2MB
static constexpr size_t OFF_P      = (size_t)BS * HWPX * 4;               // f32 [BS][NSUB][NT][4][64][4] = 29.4MB
static constexpr size_t OFF_PLQ    = OFF_P   + (size_t)BS*NSUB*NT*1024*4; // f32 [BS][NSUB][NT][64] = 1.8MB
static constexpr size_t OFF_X      = OFF_PLQ + (size_t)BS*NSUB*NT*64*4;   // f32 [BS][112][32]
static constexpr size_t OFF_S      = OFF_X   + (size_t)BS*NROWS*32*4;
static constexpr size_t OFF_LQS    = OFF_S   + (size_t)BS*NROWS*32*4;     // f32 [BS][112]

__device__ __forceinline__ float fast_rcp(float x){
#if __has_builtin(__builtin_amdgcn_rcpf)
    return __builtin_amdgcn_rcpf(x);
#else
    return 1.0f / x;
#endif
}

__device__ __forceinline__ short8 mk8(const u32 w[4]){
    union { u32 u[4]; short8 v; } c;
    c.u[0] = w[0]; c.u[1] = w[1]; c.u[2] = w[2]; c.u[3] = w[3];
    return c.v;
}

// pack two f32 -> one u32 of 2 bf16 (RNE); scalar casts let compiler fuse v_cvt_pk_bf16_f32
__device__ __forceinline__ u32 pkbf(float lo, float hi){
    __hip_bfloat16 bl = __float2bfloat16(lo);
    __hip_bfloat16 bh = __float2bfloat16(hi);
    unsigned short ul, uh;
    __builtin_memcpy(&ul, &bl, 2);
    __builtin_memcpy(&uh, &bh, 2);
    return (u32)ul | ((u32)uh << 16);
}

// ---- pack 20 binary masks into one u32 per pixel (4 px/thread) + zero d_out ----
__global__ __launch_bounds__(256) void k_pack(const int* __restrict__ gt, u32* __restrict__ packed,
                                              float* __restrict__ out){
    if (blockIdx.x == 0 && threadIdx.x < 4) out[threadIdx.x] = 0.0f;
    int i4 = blockIdx.x * 256 + threadIdx.x;      // 0 .. BS*HWPX/4-1
    int base = i4 * 4;
    int b = base >> 18;
    int pix = base & (HWPX - 1);
    const int* g = gt + ((size_t)b * MG << 18) + pix;
    u32 w0 = 0, w1 = 0, w2 = 0, w3 = 0;
#pragma unroll
    for (int m = 0; m < MG; m++){
        int4 v = *(const int4*)(g + ((size_t)m << 18));
        w0 |= ((u32)v.x & 1u) << m;
        w1 |= ((u32)v.y & 1u) << m;
        w2 |= ((u32)v.z & 1u) << m;
        w3 |= ((u32)v.w & 1u) << m;
    }
    *(uint4*)(packed + ((size_t)b << 18) + pix) = make_uint4(w0, w1, w2, w3);
}

// ---- heavy kernel: X[n,m], S[n,m] via MFMA; per-wave partial stores, NO atomics ----
__global__ __launch_bounds__(256) void k_main(const float* __restrict__ mlog, const u32* __restrict__ pkd,
                                              float* __restrict__ Ppart, float* __restrict__ Plq){
    int blk = blockIdx.x;                 // [BS * NCHUNK * NT]
    int tile = blk % NT;
    int rest = blk / NT;
    int chunk = rest % NCHUNK;
    int b = rest / NCHUNK;
    int t = threadIdx.x;
    int wave = t >> 6, lane = t & 63;
    int lr = lane & 15;                   // A-row-in-tile / B-col
    int kq = lane >> 4;                   // k-quarter
    int row = tile * 16 + lr;             // global n row (0..111)
    bool real = row < NQ;
    int rowc = real ? row : (NQ - 1);

    const float* xrow = mlog + ((size_t)b * NQ + rowc) * HWPX;
    const u32* pk = pkd + ((size_t)b << 18);
    int pxbase = chunk * CHUNK + wave * WSUB + kq * 8;

    // B-expansion per-lane constants
    u32 bsel1 = 1u << lr;                               // tile1: mask bit lr
    u32 bsel2 = (lr < 4) ? (0x10000u << lr) : 0u;       // tile2: masks 16..19
    u32 bforce = (lr == 4) ? 0x3F80u : 0u;              // tile2 col 20 = ones

    f32x4 accX0 = {0,0,0,0}, accX1 = {0,0,0,0}, accS0 = {0,0,0,0}, accS1 = {0,0,0,0};
    float lqacc = 0.0f;

#pragma unroll 2
    for (int s = 0; s < KSTEPS; s++){
        int px = pxbase + s * 32;
        f32x4 xa = *(const f32x4*)(xrow + px);
        f32x4 xb = *(const f32x4*)(xrow + px + 4);
        uint4 wa = *(const uint4*)(pk + px);
        uint4 wb = *(const uint4*)(pk + px + 4);
        u32 w[8]  = {wa.x, wa.y, wa.z, wa.w, wb.x, wb.y, wb.z, wb.w};
        float x[8] = {xa[0], xa[1], xa[2], xa[3], xb[0], xb[1], xb[2], xb[3]};

        u32 axw[4], apw[4], b1w[4], b2w[4];
#pragma unroll
        for (int jj = 0; jj < 4; jj++){
            float x0 = x[2*jj], x1 = x[2*jj+1];
            float e0 = __expf(-x0), e1 = __expf(-x1);
            float d0 = 1.0f + e0,   d1 = 1.0f + e1;
            float p0 = fast_rcp(d0), p1 = fast_rcp(d1);
            float lq0 = -__logf(d0) - x0;      // log(1 - sigmoid(x))
            float lq1 = -__logf(d1) - x1;
            lqacc += lq0 + lq1;
            axw[jj] = pkbf(x0, x1);
            apw[jj] = pkbf(p0, p1);
            u32 wl = w[2*jj], wh = w[2*jj+1];
            u32 t1l = (wl & bsel1) ? 0x3F80u : 0u;
            u32 t1h = (wh & bsel1) ? 0x3F80u : 0u;
            u32 t2l = ((wl & bsel2) ? 0x3F80u : 0u) | bforce;
            u32 t2h = ((wh & bsel2) ? 0x3F80u : 0u) | bforce;
            b1w[jj] = t1l | (t1h << 16);
            b2w[jj] = t2l | (t2h << 16);
        }
        if (!real){
#pragma unroll
            for (int jj = 0; jj < 4; jj++){ axw[jj] = 0x3F803F80u; apw[jj] = 0x3F803F80u; }
        }
        short8 Ax = mk8(axw), Ap = mk8(apw), B0 = mk8(b1w), B1 = mk8(b2w);
        accX0 = __builtin_amdgcn_mfma_f32_16x16x32_bf16(Ax, B0, accX0, 0, 0, 0);
        accX1 = __builtin_amdgcn_mfma_f32_16x16x32_bf16(Ax, B1, accX1, 0, 0, 0);
        accS0 = __builtin_amdgcn_mfma_f32_16x16x32_bf16(Ap, B0, accS0, 0, 0, 0);
        accS1 = __builtin_amdgcn_mfma_f32_16x16x32_bf16(Ap, B1, accS1, 0, 0, 0);
    }

    // contention-free partial stores: register-layout, fully coalesced (1KB per wave-store)
    int sub = chunk * 4 + wave;
    size_t pbase = (((size_t)(b * NSUB + sub) * NT + tile) * 4) * 256;
    float* dst = Ppart + pbase;
    *(f32x4*)(dst + 0*256 + lane*4) = accX0;
    *(f32x4*)(dst + 1*256 + lane*4) = accX1;
    *(f32x4*)(dst + 2*256 + lane*4) = accS0;
    *(f32x4*)(dst + 3*256 + lane*4) = accS1;
    Plq[((size_t)(b * NSUB + sub) * NT + tile) * 64 + lane] = lqacc;
}

// ---- reduce partials -> Xg/Sg/lqs (overwrites; no zeroing needed) ----
__global__ __launch_bounds__(256) void k_reduce(const float* __restrict__ P, const float* __restrict__ Plq,
                                                float* __restrict__ Xg, float* __restrict__ Sg,
                                                float* __restrict__ lqs){
    int b = blockIdx.x / NT, tile = blockIdx.x % NT;
    int t = threadIdx.x;
    float a0 = 0.f, a1 = 0.f, a2 = 0.f, a3 = 0.f;
    for (int sub = 0; sub < NSUB; ++sub){
        const float* base = P + ((size_t)(b * NSUB + sub) * NT + tile) * 1024;
        a0 += base[t];
        a1 += base[t + 256];
        a2 += base[t + 512];
        a3 += base[t + 768];
    }
    // cell t: lane = t>>2, reg = t&3 -> row=(lane>>4)*4+reg, col=lane&15 [m89 C/D layout]
    int row = ((t >> 6) << 2) + (t & 3);
    int col = (t >> 2) & 15;
    size_t o = ((size_t)b * NROWS + tile * 16 + row) * 32;
    Xg[o + col]      = a0;
    Xg[o + 16 + col] = a1;
    Sg[o + col]      = a2;
    Sg[o + 16 + col] = a3;

    // lq: 4 thread-groups each sum 128 subs for one lane, then fold kq quarters
    __shared__ float L[4][64];
    int lane = t & 63, grp = t >> 6;
    float s = 0.f;
    for (int sub = grp * (NSUB/4); sub < (grp + 1) * (NSUB/4); ++sub)
        s += Plq[((size_t)(b * NSUB + sub) * NT + tile) * 64 + lane];
    L[grp][lane] = s;
    __syncthreads();
    if (t < 16){
        float v = 0.f;
#pragma unroll
        for (int g = 0; g < 4; g++) v += L[g][t] + L[g][t+16] + L[g][t+32] + L[g][t+48];
        lqs[b * NROWS + tile * 16 + t] = v;
    }
}

// ---- fused: cost matrix + Hungarian (JV, f64, faithful) + final losses ----
__global__ __launch_bounds__(64) void k_match(const float* __restrict__ cl, const int* __restrict__ gtc,
                                              const float* __restrict__ Xg, const float* __restrict__ Sg,
                                              const float* __restrict__ lqs, float* __restrict__ out){
    __shared__ double c[MG][NQ];
    __shared__ double u[MG + 1];
    __shared__ double v[NQ + 1];
    __shared__ double minv[NQ + 1];
    __shared__ int p[NQ + 1];
    __shared__ int way[NQ + 1];
    __shared__ int used[NQ + 1];
    int b = blockIdx.x, t = threadIdx.x;

    // phase 1: cost into LDS (c[m][q], transposed like the reference JV input)
    for (int q = t; q < NQ; q += 64){
        const float* lg = cl + ((size_t)b * NQ + q) * C1;
        float l0=lg[0],l1=lg[1],l2=lg[2],l3=lg[3],l4=lg[4],l5=lg[5],l6=lg[6];
        float mx = fmaxf(fmaxf(fmaxf(l0,l1),fmaxf(l2,l3)), fmaxf(fmaxf(l4,l5),l6));
        float e0=__expf(l0-mx),e1=__expf(l1-mx),e2=__expf(l2-mx),e3=__expf(l3-mx),
              e4=__expf(l4-mx),e5=__expf(l5-mx),e6=__expf(l6-mx);
        float inv = 1.0f / (e0+e1+e2+e3+e4+e5+e6);
        float lqv = lqs[b * NROWS + q];
        float psv = Sg[((size_t)b * NROWS + q) * 32 + 20];
#pragma unroll
        for (int m = 0; m < MG; m++){
            int cc = gtc[b * MG + m];
            float ec = (cc==0)?e0:(cc==1)?e1:(cc==2)?e2:(cc==3)?e3:(cc==4)?e4:e5;
            float Xv = Xg[((size_t)b * NROWS + q) * 32 + m];
            float Sv = Sg[((size_t)b * NROWS + q) * 32 + m];
            float ysm = Xg[((size_t)b * NROWS + 100) * 32 + m];
            float bce = -(Xv + lqv) * (1.0f / (float)HWPX);
            float dice = 1.0f - (2.0f * Sv + 1.0f) / (psv + ysm + 1.0f);
            c[m][q] = (double)(2.0f * (-ec * inv) + 5.0f * bce + 5.0f * dice);
        }
    }
    for (int j = t; j <= NQ; j += 64){ v[j] = 0.0; p[j] = 0; way[j] = 0; }
    if (t <= MG) u[t] = 0.0;
    __syncthreads();

    // phase 2: Jonker-Volgenant on c^T equivalent ([20 rows x 100 cols])
    const double INF = 1e18;
    for (int i = 1; i <= MG; i++){
        if (t == 0) p[0] = i;
        for (int j = t; j <= NQ; j += 64){ minv[j] = INF; used[j] = 0; }
        __syncthreads();
        int j0 = 0;
        while (true){
            if (t == 0) used[j0] = 1;
            __syncthreads();
            int i0 = p[j0];
            double du = u[i0];
            for (int j = t + 1; j <= NQ; j += 64){
                if (!used[j]){
                    double cand = c[i0 - 1][j - 1] - du - v[j];
                    if (cand < minv[j]){ minv[j] = cand; way[j] = j0; }
                }
            }
            __syncthreads();
            double best = INF; int bj = NQ + 1;
            for (int j = t + 1; j <= NQ; j += 64){
                double mv = used[j] ? INF : minv[j];
                if (mv < best || (mv == best && j < bj)){ best = mv; bj = j; }
            }
#pragma unroll
            for (int off = 32; off; off >>= 1){
                double ob = __shfl_xor(best, off);
                int    oj = __shfl_xor(bj, off);
                if (ob < best || (ob == best && oj < bj)){ best = ob; bj = oj; }
            }
            int j1 = bj;
            double delta = best;
            for (int j = t; j <= NQ; j += 64){
                if (used[j]){ u[p[j]] += delta; v[j] -= delta; }
                else        { minv[j] -= delta; }
            }
            __syncthreads();
            j0 = j1;
            if (p[j0] == 0) break;
        }
        if (t == 0){
            int jj = j0;
            while (jj){ int jn = way[jj]; p[jj] = p[jn]; jj = jn; }
        }
        __syncthreads();
    }

    // phase 3: losses. p[j]=row(1-based) matched to pred col j -> target directly.
    float wnll = 0.f, wsum = 0.f, bsum = 0.f, dsum = 0.f;
    for (int q = t; q < NQ; q += 64){
        int pi = p[q + 1];
        int tg = (pi != 0) ? gtc[b * MG + (pi - 1)] : NO_OBJ_C;
        const float* lg = cl + ((size_t)b * NQ + q) * C1;
        float l0=lg[0],l1=lg[1],l2=lg[2],l3=lg[3],l4=lg[4],l5=lg[5],l6=lg[6];
        float mx = fmaxf(fmaxf(fmaxf(l0,l1),fmaxf(l2,l3)), fmaxf(fmaxf(l4,l5),l6));
        float se = __expf(l0-mx)+__expf(l1-mx)+__expf(l2-mx)+__expf(l3-mx)
                 + __expf(l4-mx)+__expf(l5-mx)+__expf(l6-mx);
        float lse = __logf(se) + mx;
        float lt = (tg==0)?l0:(tg==1)?l1:(tg==2)?l2:(tg==3)?l3:(tg==4)?l4:(tg==5)?l5:l6;
        float w = (tg == NO_OBJ_C) ? 0.1f : 1.0f;
        wnll += w * (lse - lt);
        wsum += w;
        if (pi != 0){
            int k = pi - 1;
            float Xv  = Xg[((size_t)b * NROWS + q) * 32 + k];
            float Sv  = Sg[((size_t)b * NROWS + q) * 32 + k];
            float lqv = lqs[b * NROWS + q];
            float psv = Sg[((size_t)b * NROWS + q) * 32 + 20];
            float ysm = Xg[((size_t)b * NROWS + 100) * 32 + k];
            bsum += -(Xv + lqv);
            dsum += 1.0f - (2.0f * Sv + 1.0f) / (psv + ysm + 1.0f);
        }
    }
#pragma unroll
    for (int off = 32; off; off >>= 1){
        wnll += __shfl_xor(wnll, off);
        wsum += __shfl_xor(wsum, off);
        bsum += __shfl_xor(bsum, off);
        dsum += __shfl_xor(dsum, off);
    }
    if (t == 0){
        float tc = wnll / wsum;
        float tm = bsum / ((float)MG * (float)HWPX);
        float td = dsum / (float)MG;
        atomicAdd(&out[0], 0.5f * tc);
        atomicAdd(&out[1], 0.5f * tm);
        atomicAdd(&out[2], 0.5f * td);
        atomicAdd(&out[3], 0.5f * (2.0f * tc + 5.0f * tm + 5.0f * td));
    }
}

extern "C" void kernel_launch(void* const* d_in, const int* in_sizes, int n_in,
                              void* d_out, int out_size, void* d_ws, size_t ws_size,
                              hipStream_t stream){
    const float* cls_logits  = (const float*)d_in[0];
    const float* mask_logits = (const float*)d_in[1];
    const int*   gt_classes  = (const int*)d_in[2];
    const int*   gt_masks    = (const int*)d_in[3];
    float* out = (float*)d_out;
    char* ws = (char*)d_ws;

    u32*   packed = (u32*)  (ws + OFF_PACKED);
    float* Ppart  = (float*)(ws + OFF_P);
    float* Plq    = (float*)(ws + OFF_PLQ);
    float* Xg     = (float*)(ws + OFF_X);
    float* Sg     = (float*)(ws + OFF_S);
    float* lqs    = (float*)(ws + OFF_LQS);

    hipLaunchKernelGGL(k_pack,   dim3(BS * HWPX / 1024), dim3(256), 0, stream, gt_masks, packed, out);
    hipLaunchKernelGGL(k_main,   dim3(BS * NCHUNK * NT), dim3(256), 0, stream, mask_logits, packed, Ppart, Plq);
    hipLaunchKernelGGL(k_reduce, dim3(BS * NT),          dim3(256), 0, stream, Ppart, Plq, Xg, Sg, lqs);
    hipLaunchKernelGGL(k_match,  dim3(BS),               dim3(64),  0, stream, cls_logits, gt_classes, Xg, Sg, lqs, out);
}

// Round 6
// 213.959 us; speedup vs baseline: 1.0235x; 1.0235x over previous
//
#include <hip/hip_runtime.h>
#include <hip/hip_bf16.h>

// EoMT criterion v5: tile-merged MFMA mask reductions (wave owns 2 n-tiles,
// B-expansion computed once), per-wave contention-free partials, parallel
// k_reduce, fused cost/Hungarian/losses.
// Shapes fixed: bs=2, N=100, C+1=7, H=W=512 (HW=262144), M=20.

typedef unsigned int u32;
typedef __attribute__((ext_vector_type(8))) short short8;   // 8 bf16 (4 VGPRs)
typedef __attribute__((ext_vector_type(4))) float f32x4;

#define BS 2
#define NQ 100
#define C1 7
#define HWPX 262144
#define MG 20
#define NO_OBJ_C 6
#define NROWS 112            // 7 tiles of 16: rows 0-99 real, 100-111 pad (row100 A=1 -> ysum)
#define NT 7
#define CH 512               // pixels per block
#define NCH (HWPX / CH)      // 512 chunks
#define KST (CH / 32)        // 16 k-steps per wave

// ---- workspace layout (bytes) ----
static constexpr size_t OFF_PACKED = 0;                                   // u32 [BS][HWPX] = 2MB
static constexpr size_t OFF_P      = (size_t)BS * HWPX * 4;               // f32 [BS][NCH][NT][1024] = 29.4MB
static constexpr size_t OFF_PLQ    = OFF_P   + (size_t)BS*NCH*NT*1024*4;  // f32 [BS][NCH][NT][16] = 459KB
static constexpr size_t OFF_X      = OFF_PLQ + (size_t)BS*NCH*NT*16*4;    // f32 [BS][112][32]
static constexpr size_t OFF_S      = OFF_X   + (size_t)BS*NROWS*32*4;
static constexpr size_t OFF_LQS    = OFF_S   + (size_t)BS*NROWS*32*4;     // f32 [BS][112]
static constexpr size_t ZERO_BYTES = (OFF_LQS + (size_t)BS*NROWS*4) - OFF_X;  // 58240 B

__device__ __forceinline__ float fast_rcp(float x){
#if __has_builtin(__builtin_amdgcn_rcpf)
    return __builtin_amdgcn_rcpf(x);
#else
    return 1.0f / x;
#endif
}

__device__ __forceinline__ short8 mk8(const u32 w[4]){
    union { u32 u[4]; short8 v; } c;
    c.u[0] = w[0]; c.u[1] = w[1]; c.u[2] = w[2]; c.u[3] = w[3];
    return c.v;
}

// pack two f32 -> one u32 of 2 bf16 (RNE)
__device__ __forceinline__ u32 f2bf(float f){
    u32 u = __builtin_bit_cast(u32, f);
    return (u + 0x7FFFu + ((u >> 16) & 1u)) >> 16;
}
__device__ __forceinline__ u32 pkbf(float lo, float hi){
    return f2bf(lo) | (f2bf(hi) << 16);
}

// ---- pack 20 binary masks into one u32 per pixel (4 px/thread) + zero accum/out ----
__global__ __launch_bounds__(256) void k_pack(const int* __restrict__ gt, u32* __restrict__ packed,
                                              float* __restrict__ accum, float* __restrict__ out){
    if (blockIdx.x == 0){
        f32x4 z = {0.f, 0.f, 0.f, 0.f};
        f32x4* a4 = (f32x4*)accum;
        for (int i = threadIdx.x; i < (int)(ZERO_BYTES / 16); i += 256) a4[i] = z;
        if (threadIdx.x < 4) out[threadIdx.x] = 0.0f;
    }
    int i4 = blockIdx.x * 256 + threadIdx.x;      // 0 .. BS*HWPX/4-1
    int base = i4 * 4;
    int b = base >> 18;
    int pix = base & (HWPX - 1);
    const int* g = gt + ((size_t)b * MG << 18) + pix;
    u32 w0 = 0, w1 = 0, w2 = 0, w3 = 0;
#pragma unroll
    for (int m = 0; m < MG; m++){
        int4 v = *(const int4*)(g + ((size_t)m << 18));
        w0 |= ((u32)v.x & 1u) << m;
        w1 |= ((u32)v.y & 1u) << m;
        w2 |= ((u32)v.z & 1u) << m;
        w3 |= ((u32)v.w & 1u) << m;
    }
    *(uint4*)(packed + ((size_t)b << 18) + pix) = make_uint4(w0, w1, w2, w3);
}

// ---- heavy kernel: wave owns tiles {w, w+4}; B built once; per-wave partial stores ----
__global__ __launch_bounds__(256, 4) void k_main(const float* __restrict__ mlog, const u32* __restrict__ pkd,
                                                 float* __restrict__ Ppart, float* __restrict__ Plq){
    int blk = blockIdx.x;                 // [BS * NCH]
    int chunk = blk % NCH;
    int b = blk / NCH;
    int t = threadIdx.x;
    int wave = t >> 6, lane = t & 63;
    int lr = lane & 15;                   // B col / A row-within-tile
    int kq = lane >> 4;                   // k-quarter

    int t7a = wave;                       // first tile
    int t7b = wave + 4;                   // second tile (waves 0..2 only)
    bool two = (t7b < NT);
    int rowA = t7a * 16 + lr;             // always < 100
    int rowB0 = t7b * 16 + lr;
    bool padB = two && (rowB0 >= NQ);     // tile 6, lr>=4 -> A forced to 1.0 (row100 => ysum)
    int rowB = padB ? (NQ - 1) : rowB0;

    const float* xrowA = mlog + ((size_t)b * NQ + rowA) * HWPX;
    const float* xrowB = mlog + ((size_t)b * NQ + (two ? rowB : rowA)) * HWPX;
    const u32* pk = pkd + ((size_t)b << 18);
    int pxbase = chunk * CH + kq * 8;

    // B-expansion per-lane constants
    u32 bsel1 = 1u << lr;                               // tile1 cols: mask bit lr
    u32 bsel2 = (lr < 4) ? (0x10000u << lr) : 0u;       // tile2 cols: masks 16..19
    u32 bforce = (lr == 4) ? 0x3F80u : 0u;              // tile2 col 20 = ones -> psum

    f32x4 aA0 = {0,0,0,0}, aA1 = {0,0,0,0}, aA2 = {0,0,0,0}, aA3 = {0,0,0,0};
    f32x4 aB0 = {0,0,0,0}, aB1 = {0,0,0,0}, aB2 = {0,0,0,0}, aB3 = {0,0,0,0};
    float lqA = 0.0f, lqB = 0.0f;

#pragma unroll 2
    for (int s = 0; s < KST; s++){
        int px = pxbase + s * 32;
        uint4 wa = *(const uint4*)(pk + px);
        uint4 wb = *(const uint4*)(pk + px + 4);
        f32x4 xaA = *(const f32x4*)(xrowA + px);
        f32x4 xbA = *(const f32x4*)(xrowA + px + 4);
        f32x4 xaB = *(const f32x4*)(xrowB + px);
        f32x4 xbB = *(const f32x4*)(xrowB + px + 4);
        u32 w[8]   = {wa.x, wa.y, wa.z, wa.w, wb.x, wb.y, wb.z, wb.w};
        float xA[8] = {xaA[0], xaA[1], xaA[2], xaA[3], xbA[0], xbA[1], xbA[2], xbA[3]};
        float xB[8] = {xaB[0], xaB[1], xaB[2], xaB[3], xbB[0], xbB[1], xbB[2], xbB[3]};

        u32 b1w[4], b2w[4], axA[4], apA[4], axB[4], apB[4];
#pragma unroll
        for (int jj = 0; jj < 4; jj++){
            // B expansion: ONCE per pixel-pair (shared by both tiles)
            u32 wl = w[2*jj], wh = w[2*jj+1];
            u32 t1l = (wl & bsel1) ? 0x3F80u : 0u;
            u32 t1h = (wh & bsel1) ? 0x3F80u : 0u;
            u32 t2l = ((wl & bsel2) ? 0x3F80u : 0u) | bforce;
            u32 t2h = ((wh & bsel2) ? 0x3F80u : 0u) | bforce;
            b1w[jj] = t1l | (t1h << 16);
            b2w[jj] = t2l | (t2h << 16);
            // tile A sigmoid path
            {
                float x0 = xA[2*jj], x1 = xA[2*jj+1];
                float e0 = __expf(-x0), e1 = __expf(-x1);
                float d0 = 1.0f + e0,   d1 = 1.0f + e1;
                float p0 = fast_rcp(d0), p1 = fast_rcp(d1);
                lqA += (-__logf(d0) - x0) + (-__logf(d1) - x1);
                axA[jj] = pkbf(x0, x1);
                apA[jj] = pkbf(p0, p1);
            }
            // tile B sigmoid path
            {
                float x0 = xB[2*jj], x1 = xB[2*jj+1];
                float e0 = __expf(-x0), e1 = __expf(-x1);
                float d0 = 1.0f + e0,   d1 = 1.0f + e1;
                float p0 = fast_rcp(d0), p1 = fast_rcp(d1);
                lqB += (-__logf(d0) - x0) + (-__logf(d1) - x1);
                u32 ax = pkbf(x0, x1), ap = pkbf(p0, p1);
                axB[jj] = padB ? 0x3F803F80u : ax;
                apB[jj] = padB ? 0x3F803F80u : ap;
            }
        }
        short8 B0 = mk8(b1w), B1 = mk8(b2w);
        short8 AxA = mk8(axA), ApA = mk8(apA);
        aA0 = __builtin_amdgcn_mfma_f32_16x16x32_bf16(AxA, B0, aA0, 0, 0, 0);
        aA1 = __builtin_amdgcn_mfma_f32_16x16x32_bf16(AxA, B1, aA1, 0, 0, 0);
        aA2 = __builtin_amdgcn_mfma_f32_16x16x32_bf16(ApA, B0, aA2, 0, 0, 0);
        aA3 = __builtin_amdgcn_mfma_f32_16x16x32_bf16(ApA, B1, aA3, 0, 0, 0);
        if (two){
            short8 AxB = mk8(axB), ApB = mk8(apB);
            aB0 = __builtin_amdgcn_mfma_f32_16x16x32_bf16(AxB, B0, aB0, 0, 0, 0);
            aB1 = __builtin_amdgcn_mfma_f32_16x16x32_bf16(AxB, B1, aB1, 0, 0, 0);
            aB2 = __builtin_amdgcn_mfma_f32_16x16x32_bf16(ApB, B0, aB2, 0, 0, 0);
            aB3 = __builtin_amdgcn_mfma_f32_16x16x32_bf16(ApB, B1, aB3, 0, 0, 0);
        }
    }

    // per-wave partial stores; each (b,chunk,tile) written by exactly one wave
    {
        size_t pb = (((size_t)b * NCH + chunk) * NT + t7a) * 1024;
        *(f32x4*)(Ppart + pb + 0*256 + lane*4) = aA0;
        *(f32x4*)(Ppart + pb + 1*256 + lane*4) = aA1;
        *(f32x4*)(Ppart + pb + 2*256 + lane*4) = aA2;
        *(f32x4*)(Ppart + pb + 3*256 + lane*4) = aA3;
        float lqv = lqA + __shfl_xor(lqA, 16);
        lqv += __shfl_xor(lqv, 32);
        if (lane < 16) Plq[(((size_t)b * NCH + chunk) * NT + t7a) * 16 + lane] = lqv;
    }
    if (two){
        size_t pb = (((size_t)b * NCH + chunk) * NT + t7b) * 1024;
        *(f32x4*)(Ppart + pb + 0*256 + lane*4) = aB0;
        *(f32x4*)(Ppart + pb + 1*256 + lane*4) = aB1;
        *(f32x4*)(Ppart + pb + 2*256 + lane*4) = aB2;
        *(f32x4*)(Ppart + pb + 3*256 + lane*4) = aB3;
        float lqv = lqB + __shfl_xor(lqB, 16);
        lqv += __shfl_xor(lqv, 32);
        if (lane < 16) Plq[(((size_t)b * NCH + chunk) * NT + t7b) * 16 + lane] = lqv;
    }
}

// ---- reduce partials -> Xg/Sg/lqs (atomicAdd into k_pack-zeroed accum) ----
__global__ __launch_bounds__(256) void k_reduce(const float* __restrict__ P, const float* __restrict__ Plq,
                                                float* __restrict__ Xg, float* __restrict__ Sg,
                                                float* __restrict__ lqs){
    int g = blockIdx.x;                   // [BS * NT * 16]
    int sg = g & 15;
    int tile = (g >> 4) % NT;
    int b = g / (16 * NT);
    int t = threadIdx.x;
    float a0 = 0.f, a1 = 0.f, a2 = 0.f, a3 = 0.f;
    for (int c = 0; c < NCH / 16; ++c){
        int ch = sg * (NCH / 16) + c;
        const float* base = P + (((size_t)b * NCH + ch) * NT + tile) * 1024;
        a0 += base[t];
        a1 += base[t + 256];
        a2 += base[t + 512];
        a3 += base[t + 768];
    }
    // cell t: lane = t>>2, reg = t&3 -> row=(lane>>4)*4+reg, col=lane&15 [m89 C/D layout]
    int row = ((t >> 6) << 2) + (t & 3);
    int col = (t >> 2) & 15;
    size_t o = ((size_t)b * NROWS + tile * 16 + row) * 32;
    atomicAdd(&Xg[o + col],      a0);
    atomicAdd(&Xg[o + 16 + col], a1);
    atomicAdd(&Sg[o + col],      a2);
    atomicAdd(&Sg[o + 16 + col], a3);
    if (t < 16){
        float s = 0.f;
        for (int c = 0; c < NCH / 16; ++c){
            int ch = sg * (NCH / 16) + c;
            s += Plq[(((size_t)b * NCH + ch) * NT + tile) * 16 + t];
        }
        atomicAdd(&lqs[b * NROWS + tile * 16 + t], s);
    }
}

// ---- fused: cost matrix + Hungarian (JV, f64, faithful) + final losses ----
__global__ __launch_bounds__(64) void k_match(const float* __restrict__ cl, const int* __restrict__ gtc,
                                              const float* __restrict__ Xg, const float* __restrict__ Sg,
                                              const float* __restrict__ lqs, float* __restrict__ out){
    __shared__ double c[MG][NQ];
    __shared__ double u[MG + 1];
    __shared__ double v[NQ + 1];
    __shared__ double minv[NQ + 1];
    __shared__ int p[NQ + 1];
    __shared__ int way[NQ + 1];
    __shared__ int used[NQ + 1];
    int b = blockIdx.x, t = threadIdx.x;

    // phase 1: cost into LDS (c[m][q], transposed like the reference JV input)
    for (int q = t; q < NQ; q += 64){
        const float* lg = cl + ((size_t)b * NQ + q) * C1;
        float l0=lg[0],l1=lg[1],l2=lg[2],l3=lg[3],l4=lg[4],l5=lg[5],l6=lg[6];
        float mx = fmaxf(fmaxf(fmaxf(l0,l1),fmaxf(l2,l3)), fmaxf(fmaxf(l4,l5),l6));
        float e0=__expf(l0-mx),e1=__expf(l1-mx),e2=__expf(l2-mx),e3=__expf(l3-mx),
              e4=__expf(l4-mx),e5=__expf(l5-mx),e6=__expf(l6-mx);
        float inv = 1.0f / (e0+e1+e2+e3+e4+e5+e6);
        float lqv = lqs[b * NROWS + q];
        float psv = Sg[((size_t)b * NROWS + q) * 32 + 20];
#pragma unroll
        for (int m = 0; m < MG; m++){
            int cc = gtc[b * MG + m];
            float ec = (cc==0)?e0:(cc==1)?e1:(cc==2)?e2:(cc==3)?e3:(cc==4)?e4:e5;
            float Xv = Xg[((size_t)b * NROWS + q) * 32 + m];
            float Sv = Sg[((size_t)b * NROWS + q) * 32 + m];
            float ysm = Xg[((size_t)b * NROWS + 100) * 32 + m];
            float bce = -(Xv + lqv) * (1.0f / (float)HWPX);
            float dice = 1.0f - (2.0f * Sv + 1.0f) / (psv + ysm + 1.0f);
            c[m][q] = (double)(2.0f * (-ec * inv) + 5.0f * bce + 5.0f * dice);
        }
    }
    for (int j = t; j <= NQ; j += 64){ v[j] = 0.0; p[j] = 0; way[j] = 0; }
    if (t <= MG) u[t] = 0.0;
    __syncthreads();

    // phase 2: Jonker-Volgenant on c^T equivalent ([20 rows x 100 cols])
    const double INF = 1e18;
    for (int i = 1; i <= MG; i++){
        if (t == 0) p[0] = i;
        for (int j = t; j <= NQ; j += 64){ minv[j] = INF; used[j] = 0; }
        __syncthreads();
        int j0 = 0;
        while (true){
            if (t == 0) used[j0] = 1;
            __syncthreads();
            int i0 = p[j0];
            double du = u[i0];
            for (int j = t + 1; j <= NQ; j += 64){
                if (!used[j]){
                    double cand = c[i0 - 1][j - 1] - du - v[j];
                    if (cand < minv[j]){ minv[j] = cand; way[j] = j0; }
                }
            }
            __syncthreads();
            double best = INF; int bj = NQ + 1;
            for (int j = t + 1; j <= NQ; j += 64){
                double mv = used[j] ? INF : minv[j];
                if (mv < best || (mv == best && j < bj)){ best = mv; bj = j; }
            }
#pragma unroll
            for (int off = 32; off; off >>= 1){
                double ob = __shfl_xor(best, off);
                int    oj = __shfl_xor(bj, off);
                if (ob < best || (ob == best && oj < bj)){ best = ob; bj = oj; }
            }
            int j1 = bj;
            double delta = best;
            for (int j = t; j <= NQ; j += 64){
                if (used[j]){ u[p[j]] += delta; v[j] -= delta; }
                else        { minv[j] -= delta; }
            }
            __syncthreads();
            j0 = j1;
            if (p[j0] == 0) break;
        }
        if (t == 0){
            int jj = j0;
            while (jj){ int jn = way[jj]; p[jj] = p[jn]; jj = jn; }
        }
        __syncthreads();
    }

    // phase 3: losses. p[j]=row(1-based) matched to pred col j -> target directly.
    float wnll = 0.f, wsum = 0.f, bsum = 0.f, dsum = 0.f;
    for (int q = t; q < NQ; q += 64){
        int pi = p[q + 1];
        int tg = (pi != 0) ? gtc[b * MG + (pi - 1)] : NO_OBJ_C;
        const float* lg = cl + ((size_t)b * NQ + q) * C1;
        float l0=lg[0],l1=lg[1],l2=lg[2],l3=lg[3],l4=lg[4],l5=lg[5],l6=lg[6];
        float mx = fmaxf(fmaxf(fmaxf(l0,l1),fmaxf(l2,l3)), fmaxf(fmaxf(l4,l5),l6));
        float se = __expf(l0-mx)+__expf(l1-mx)+__expf(l2-mx)+__expf(l3-mx)
                 + __expf(l4-mx)+__expf(l5-mx)+__expf(l6-mx);
        float lse = __logf(se) + mx;
        float lt = (tg==0)?l0:(tg==1)?l1:(tg==2)?l2:(tg==3)?l3:(tg==4)?l4:(tg==5)?l5:l6;
        float w = (tg == NO_OBJ_C) ? 0.1f : 1.0f;
        wnll += w * (lse - lt);
        wsum += w;
        if (pi != 0){
            int k = pi - 1;
            float Xv  = Xg[((size_t)b * NROWS + q) * 32 + k];
            float Sv  = Sg[((size_t)b * NROWS + q) * 32 + k];
            float lqv = lqs[b * NROWS + q];
            float psv = Sg[((size_t)b * NROWS + q) * 32 + 20];
            float ysm = Xg[((size_t)b * NROWS + 100) * 32 + k];
            bsum += -(Xv + lqv);
            dsum += 1.0f - (2.0f * Sv + 1.0f) / (psv + ysm + 1.0f);
        }
    }
#pragma unroll
    for (int off = 32; off; off >>= 1){
        wnll += __shfl_xor(wnll, off);
        wsum += __shfl_xor(wsum, off);
        bsum += __shfl_xor(bsum, off);
        dsum += __shfl_xor(dsum, off);
    }
    if (t == 0){
        float tc = wnll / wsum;
        float tm = bsum / ((float)MG * (float)HWPX);
        float td = dsum / (float)MG;
        atomicAdd(&out[0], 0.5f * tc);
        atomicAdd(&out[1], 0.5f * tm);
        atomicAdd(&out[2], 0.5f * td);
        atomicAdd(&out[3], 0.5f * (2.0f * tc + 5.0f * tm + 5.0f * td));
    }
}

extern "C" void kernel_launch(void* const* d_in, const int* in_sizes, int n_in,
                              void* d_out, int out_size, void* d_ws, size_t ws_size,
                              hipStream_t stream){
    const float* cls_logits  = (const float*)d_in[0];
    const float* mask_logits = (const float*)d_in[1];
    const int*   gt_classes  = (const int*)d_in[2];
    const int*   gt_masks    = (const int*)d_in[3];
    float* out = (float*)d_out;
    char* ws = (char*)d_ws;

    u32*   packed = (u32*)  (ws + OFF_PACKED);
    float* Ppart  = (float*)(ws + OFF_P);
    float* Plq    = (float*)(ws + OFF_PLQ);
    float* Xg     = (float*)(ws + OFF_X);
    float* Sg     = (float*)(ws + OFF_S);
    float* lqs    = (float*)(ws + OFF_LQS);

    hipLaunchKernelGGL(k_pack,   dim3(BS * HWPX / 1024), dim3(256), 0, stream, gt_masks, packed, Xg, out);
    hipLaunchKernelGGL(k_main,   dim3(BS * NCH),         dim3(256), 0, stream, mask_logits, packed, Ppart, Plq);
    hipLaunchKernelGGL(k_reduce, dim3(BS * NT * 16),     dim3(256), 0, stream, Ppart, Plq, Xg, Sg, lqs);
    hipLaunchKernelGGL(k_match,  dim3(BS),               dim3(64),  0, stream, cls_logits, gt_classes, Xg, Sg, lqs, out);
}

// Round 7
// 179.679 us; speedup vs baseline: 1.2188x; 1.1908x over previous
//
#include <hip/hip_runtime.h>

// EoMT criterion v6: 32x32x16 MFMA (one B-operand covers all 20 masks + psum col),
// 2048-block grid, prefetched k-loop, contention-free partials + parallel reduce,
// fused cost/Hungarian/losses. Shapes fixed: bs=2, N=100, C+1=7, HW=512^2, M=20.

typedef unsigned int u32;
typedef __attribute__((ext_vector_type(8))) short short8;    // 8 bf16 (4 VGPRs)
typedef __attribute__((ext_vector_type(4))) float f32x4;
typedef __attribute__((ext_vector_type(16))) float f32x16;

#define BS 2
#define NQ 100
#define C1 7
#define HWPX 262144
#define MG 20
#define NO_OBJ_C 6
#define NR2 128              // 4 tiles of 32 rows; rows 100..127 pad (row 100: A=1 -> ysum)
#define NTL 4
#define CH 256               // pixels per block
#define NCH (HWPX / CH)      // 1024
#define KST (CH / 16)        // 16 k-steps (K=16 per MFMA)
#define RED_SUB 64
#define RED_CH (NCH / RED_SUB)  // 16

// ---- workspace layout (bytes); harness ws ~838MB ----
static constexpr size_t OFF_PACKED = 0;                                   // u32 [BS][HWPX] = 2MB
static constexpr size_t OFF_P      = (size_t)BS * HWPX * 4;               // f32 [BS][NCH][NTL][2048] = 64MB
static constexpr size_t SZ_P       = (size_t)BS * NCH * NTL * 2048 * 4;
static constexpr size_t OFF_PLQ    = OFF_P + SZ_P;                        // f32 [BS][NCH][NTL][32] = 1MB
static constexpr size_t SZ_PLQ     = (size_t)BS * NCH * NTL * 32 * 4;
static constexpr size_t OFF_X      = OFF_PLQ + SZ_PLQ;                    // f32 [BS][128][32]
static constexpr size_t OFF_S      = OFF_X + (size_t)BS * NR2 * 32 * 4;
static constexpr size_t OFF_LQS    = OFF_S + (size_t)BS * NR2 * 32 * 4;   // f32 [BS][128]
static constexpr size_t ZERO_BYTES = (OFF_LQS + (size_t)BS * NR2 * 4) - OFF_X;  // 66560

__device__ __forceinline__ float fast_rcp(float x){
#if __has_builtin(__builtin_amdgcn_rcpf)
    return __builtin_amdgcn_rcpf(x);
#else
    return 1.0f / x;
#endif
}

__device__ __forceinline__ short8 mk8_4(u32 a, u32 b, u32 c, u32 d){
    union { u32 u[4]; short8 v; } t;
    t.u[0] = a; t.u[1] = b; t.u[2] = c; t.u[3] = d;
    return t.v;
}

// truncation pack: two f32 -> u32 of 2 bf16 (bias ~0.2% rel, absorbed by 0.17 threshold)
__device__ __forceinline__ u32 pkt(float lo, float hi){
    u32 ul = __builtin_bit_cast(u32, lo), uh = __builtin_bit_cast(u32, hi);
    return (uh & 0xFFFF0000u) | (ul >> 16);
}

// ---- pack 20 binary masks into one u32 per pixel + zero accum/out ----
__global__ __launch_bounds__(256) void k_pack(const int* __restrict__ gt, u32* __restrict__ packed,
                                              float* __restrict__ accum, float* __restrict__ out){
    if (blockIdx.x == 0){
        f32x4 z = {0.f, 0.f, 0.f, 0.f};
        f32x4* a4 = (f32x4*)accum;
        for (int i = threadIdx.x; i < (int)(ZERO_BYTES / 16); i += 256) a4[i] = z;
        if (threadIdx.x < 4) out[threadIdx.x] = 0.0f;
    }
    int i4 = blockIdx.x * 256 + threadIdx.x;      // 0 .. BS*HWPX/4-1
    int base = i4 * 4;
    int b = base >> 18;
    int pix = base & (HWPX - 1);
    const int* g = gt + ((size_t)b * MG << 18) + pix;
    u32 w0 = 0, w1 = 0, w2 = 0, w3 = 0;
#pragma unroll
    for (int m = 0; m < MG; m++){
        int4 v = *(const int4*)(g + ((size_t)m << 18));
        w0 |= ((u32)v.x & 1u) << m;
        w1 |= ((u32)v.y & 1u) << m;
        w2 |= ((u32)v.z & 1u) << m;
        w3 |= ((u32)v.w & 1u) << m;
    }
    *(uint4*)(packed + ((size_t)b << 18) + pix) = make_uint4(w0, w1, w2, w3);
}

// ---- heavy kernel: wave = 32-row tile; one MFMA pair per 16 px ----
__global__ __launch_bounds__(256) void k_main(const float* __restrict__ mlog, const u32* __restrict__ pkd,
                                              float* __restrict__ Ppart, float* __restrict__ Plq){
    int blk = blockIdx.x;                 // [BS * NCH] = 2048
    int chunk = blk % NCH;
    int b = blk / NCH;
    int t = threadIdx.x;
    int wave = t >> 6, lane = t & 63;
    int r = lane & 31, kq = lane >> 5;
    int row = wave * 32 + r;
    bool pad = row >= NQ;                 // pad rows read row 99 (broadcast), A forced to 1.0
    int rowc = pad ? (NQ - 1) : row;

    const float* xp = mlog + ((size_t)b * NQ + rowc) * HWPX + chunk * CH + kq * 8;
    const u32*   wp = pkd + ((size_t)b << 18) + chunk * CH + kq * 8;

    // B column constants: col<20 -> mask bit col; col 20 -> ones (psum); col>20 -> 0
    int c = lane & 31;
    u32 shc  = (c < MG) ? (u32)c : 0u;
    u32 andm = (c < MG) ? 1u : 0u;
    u32 orm  = (c == MG) ? 1u : 0u;

    f32x16 accX = {0,0,0,0,0,0,0,0,0,0,0,0,0,0,0,0};
    f32x16 accS = {0,0,0,0,0,0,0,0,0,0,0,0,0,0,0,0};
    float lqacc = 0.0f;

    auto bpair = [&](u32 wl, u32 wh) -> u32 {
        u32 bl = ((wl >> shc) & andm) | orm;
        u32 bh = ((wh >> shc) & andm) | orm;
        return (bl | (bh << 16)) * 0x3F80u;     // {0,1} -> bf16 {0,1.0} packed
    };
    auto step = [&](f32x4 XA, f32x4 XB, uint4 WA, uint4 WB){
        float x0=XA[0],x1=XA[1],x2=XA[2],x3=XA[3];
        float x4=XB[0],x5=XB[1],x6=XB[2],x7=XB[3];
        float e0=__expf(-x0),e1=__expf(-x1),e2=__expf(-x2),e3=__expf(-x3);
        float e4=__expf(-x4),e5=__expf(-x5),e6=__expf(-x6),e7=__expf(-x7);
        float d0=1.f+e0,d1=1.f+e1,d2=1.f+e2,d3=1.f+e3;
        float d4=1.f+e4,d5=1.f+e5,d6=1.f+e6,d7=1.f+e7;
        float p0=fast_rcp(d0),p1=fast_rcp(d1),p2=fast_rcp(d2),p3=fast_rcp(d3);
        float p4=fast_rcp(d4),p5=fast_rcp(d5),p6=fast_rcp(d6),p7=fast_rcp(d7);
        // sum log(1-sigmoid(x)) = -log(prod d) - sum x   (one log per 8 px)
        float pr = ((d0*d1)*(d2*d3))*((d4*d5)*(d6*d7));
        lqacc -= __logf(pr) + (((x0+x1)+(x2+x3))+((x4+x5)+(x6+x7)));
        u32 a0 = pad ? 0x3F803F80u : pkt(x0,x1);
        u32 a1 = pad ? 0x3F803F80u : pkt(x2,x3);
        u32 a2 = pad ? 0x3F803F80u : pkt(x4,x5);
        u32 a3 = pad ? 0x3F803F80u : pkt(x6,x7);
        u32 q0 = pkt(p0,p1), q1 = pkt(p2,p3), q2 = pkt(p4,p5), q3 = pkt(p6,p7);
        u32 b0 = bpair(WA.x, WA.y), b1 = bpair(WA.z, WA.w);
        u32 b2 = bpair(WB.x, WB.y), b3 = bpair(WB.z, WB.w);
        short8 Av = mk8_4(a0,a1,a2,a3);
        short8 Qv = mk8_4(q0,q1,q2,q3);
        short8 Bv = mk8_4(b0,b1,b2,b3);
        accX = __builtin_amdgcn_mfma_f32_32x32x16_bf16(Av, Bv, accX, 0, 0, 0);
        accS = __builtin_amdgcn_mfma_f32_32x32x16_bf16(Qv, Bv, accS, 0, 0, 0);
    };

    // 1-deep prefetch pipeline, 2-step unrolled (static buffer names)
    f32x4 xa0 = *(const f32x4*)(xp);
    f32x4 xb0 = *(const f32x4*)(xp + 4);
    uint4 wa0 = *(const uint4*)(wp);
    uint4 wb0 = *(const uint4*)(wp + 4);
    f32x4 xa1, xb1; uint4 wa1, wb1;
    for (int s = 0; s < KST; s += 2){
        xa1 = *(const f32x4*)(xp + (s+1)*16);
        xb1 = *(const f32x4*)(xp + (s+1)*16 + 4);
        wa1 = *(const uint4*)(wp + (s+1)*16);
        wb1 = *(const uint4*)(wp + (s+1)*16 + 4);
        step(xa0, xb0, wa0, wb0);
        if (s + 2 < KST){
            xa0 = *(const f32x4*)(xp + (s+2)*16);
            xb0 = *(const f32x4*)(xp + (s+2)*16 + 4);
            wa0 = *(const uint4*)(wp + (s+2)*16);
            wb0 = *(const uint4*)(wp + (s+2)*16 + 4);
        }
        step(xa1, xb1, wa1, wb1);
    }

    // contention-free partial stores: X[1024] then S[1024] per (b,chunk,tile)
    size_t pb = (((size_t)b * NCH + chunk) * NTL + wave) * 2048;
#pragma unroll
    for (int p = 0; p < 4; p++){
        f32x4 vx = { accX[4*p], accX[4*p+1], accX[4*p+2], accX[4*p+3] };
        f32x4 vs = { accS[4*p], accS[4*p+1], accS[4*p+2], accS[4*p+3] };
        *(f32x4*)(Ppart + pb + p*256 + lane*4) = vx;
        *(f32x4*)(Ppart + pb + 1024 + p*256 + lane*4) = vs;
    }
    lqacc += __shfl_xor(lqacc, 32);       // fold kq halves; lanes 0..31 hold row totals
    if (lane < 32) Plq[(((size_t)b * NCH + chunk) * NTL + wave) * 32 + lane] = lqacc;
}

// ---- reduce partials -> Xg/Sg/lqs (atomicAdd into k_pack-zeroed accum) ----
__global__ __launch_bounds__(256) void k_reduce(const float* __restrict__ P, const float* __restrict__ Plq,
                                                float* __restrict__ Xg, float* __restrict__ Sg,
                                                float* __restrict__ lqs){
    int g = blockIdx.x;                   // [BS * NTL * RED_SUB] = 512
    int sub = g % RED_SUB;
    int tile = (g / RED_SUB) % NTL;
    int b = g / (RED_SUB * NTL);
    int t = threadIdx.x;
    f32x4 ax = {0,0,0,0}, as = {0,0,0,0};
    for (int i = 0; i < RED_CH; i++){
        int ch = sub * RED_CH + i;
        const float* base = P + (((size_t)b * NCH + ch) * NTL + tile) * 2048;
        ax += *(const f32x4*)(base + t*4);
        as += *(const f32x4*)(base + 1024 + t*4);
    }
    // 32x32 C/D layout [m74/m101]: col=lane&31, row=(reg&3)+8*(reg>>2)+4*(lane>>5)
    int p = t >> 6, l = t & 63;
    int col = l & 31;
#pragma unroll
    for (int j = 0; j < 4; j++){
        int row32 = j + 8*p + 4*(l >> 5);
        size_t o = ((size_t)b * NR2 + tile*32 + row32) * 32 + col;
        atomicAdd(&Xg[o], ax[j]);
        atomicAdd(&Sg[o], as[j]);
    }
    if (t < 32){
        float s = 0.f;
        for (int i = 0; i < RED_CH; i++){
            int ch = sub * RED_CH + i;
            s += Plq[(((size_t)b * NCH + ch) * NTL + tile) * 32 + t];
        }
        atomicAdd(&lqs[b * NR2 + tile*32 + t], s);
    }
}

// ---- fused: cost matrix + Hungarian (JV, f64, faithful) + final losses ----
__global__ __launch_bounds__(64) void k_match(const float* __restrict__ cl, const int* __restrict__ gtc,
                                              const float* __restrict__ Xg, const float* __restrict__ Sg,
                                              const float* __restrict__ lqs, float* __restrict__ out){
    __shared__ double c[MG][NQ];
    __shared__ double u[MG + 1];
    __shared__ double v[NQ + 1];
    __shared__ double minv[NQ + 1];
    __shared__ int p[NQ + 1];
    __shared__ int way[NQ + 1];
    __shared__ int used[NQ + 1];
    int b = blockIdx.x, t = threadIdx.x;

    for (int q = t; q < NQ; q += 64){
        const float* lg = cl + ((size_t)b * NQ + q) * C1;
        float l0=lg[0],l1=lg[1],l2=lg[2],l3=lg[3],l4=lg[4],l5=lg[5],l6=lg[6];
        float mx = fmaxf(fmaxf(fmaxf(l0,l1),fmaxf(l2,l3)), fmaxf(fmaxf(l4,l5),l6));
        float e0=__expf(l0-mx),e1=__expf(l1-mx),e2=__expf(l2-mx),e3=__expf(l3-mx),
              e4=__expf(l4-mx),e5=__expf(l5-mx),e6=__expf(l6-mx);
        float inv = 1.0f / (e0+e1+e2+e3+e4+e5+e6);
        float lqv = lqs[b * NR2 + q];
        float psv = Sg[((size_t)b * NR2 + q) * 32 + 20];
#pragma unroll
        for (int m = 0; m < MG; m++){
            int cc = gtc[b * MG + m];
            float ec = (cc==0)?e0:(cc==1)?e1:(cc==2)?e2:(cc==3)?e3:(cc==4)?e4:e5;
            float Xv = Xg[((size_t)b * NR2 + q) * 32 + m];
            float Sv = Sg[((size_t)b * NR2 + q) * 32 + m];
            float ysm = Xg[((size_t)b * NR2 + 100) * 32 + m];
            float bce = -(Xv + lqv) * (1.0f / (float)HWPX);
            float dice = 1.0f - (2.0f * Sv + 1.0f) / (psv + ysm + 1.0f);
            c[m][q] = (double)(2.0f * (-ec * inv) + 5.0f * bce + 5.0f * dice);
        }
    }
    for (int j = t; j <= NQ; j += 64){ v[j] = 0.0; p[j] = 0; way[j] = 0; }
    if (t <= MG) u[t] = 0.0;
    __syncthreads();

    const double INF = 1e18;
    for (int i = 1; i <= MG; i++){
        if (t == 0) p[0] = i;
        for (int j = t; j <= NQ; j += 64){ minv[j] = INF; used[j] = 0; }
        __syncthreads();
        int j0 = 0;
        while (true){
            if (t == 0) used[j0] = 1;
            __syncthreads();
            int i0 = p[j0];
            double du = u[i0];
            for (int j = t + 1; j <= NQ; j += 64){
                if (!used[j]){
                    double cand = c[i0 - 1][j - 1] - du - v[j];
                    if (cand < minv[j]){ minv[j] = cand; way[j] = j0; }
                }
            }
            __syncthreads();
            double best = INF; int bj = NQ + 1;
            for (int j = t + 1; j <= NQ; j += 64){
                double mv = used[j] ? INF : minv[j];
                if (mv < best || (mv == best && j < bj)){ best = mv; bj = j; }
            }
#pragma unroll
            for (int off = 32; off; off >>= 1){
                double ob = __shfl_xor(best, off);
                int    oj = __shfl_xor(bj, off);
                if (ob < best || (ob == best && oj < bj)){ best = ob; bj = oj; }
            }
            int j1 = bj;
            double delta = best;
            for (int j = t; j <= NQ; j += 64){
                if (used[j]){ u[p[j]] += delta; v[j] -= delta; }
                else        { minv[j] -= delta; }
            }
            __syncthreads();
            j0 = j1;
            if (p[j0] == 0) break;
        }
        if (t == 0){
            int jj = j0;
            while (jj){ int jn = way[jj]; p[jj] = p[jn]; jj = jn; }
        }
        __syncthreads();
    }

    float wnll = 0.f, wsum = 0.f, bsum = 0.f, dsum = 0.f;
    for (int q = t; q < NQ; q += 64){
        int pi = p[q + 1];
        int tg = (pi != 0) ? gtc[b * MG + (pi - 1)] : NO_OBJ_C;
        const float* lg = cl + ((size_t)b * NQ + q) * C1;
        float l0=lg[0],l1=lg[1],l2=lg[2],l3=lg[3],l4=lg[4],l5=lg[5],l6=lg[6];
        float mx = fmaxf(fmaxf(fmaxf(l0,l1),fmaxf(l2,l3)), fmaxf(fmaxf(l4,l5),l6));
        float se = __expf(l0-mx)+__expf(l1-mx)+__expf(l2-mx)+__expf(l3-mx)
                 + __expf(l4-mx)+__expf(l5-mx)+__expf(l6-mx);
        float lse = __logf(se) + mx;
        float lt = (tg==0)?l0:(tg==1)?l1:(tg==2)?l2:(tg==3)?l3:(tg==4)?l4:(tg==5)?l5:l6;
        float w = (tg == NO_OBJ_C) ? 0.1f : 1.0f;
        wnll += w * (lse - lt);
        wsum += w;
        if (pi != 0){
            int k = pi - 1;
            float Xv  = Xg[((size_t)b * NR2 + q) * 32 + k];
            float Sv  = Sg[((size_t)b * NR2 + q) * 32 + k];
            float lqv = lqs[b * NR2 + q];
            float psv = Sg[((size_t)b * NR2 + q) * 32 + 20];
            float ysm = Xg[((size_t)b * NR2 + 100) * 32 + k];
            bsum += -(Xv + lqv);
            dsum += 1.0f - (2.0f * Sv + 1.0f) / (psv + ysm + 1.0f);
        }
    }
#pragma unroll
    for (int off = 32; off; off >>= 1){
        wnll += __shfl_xor(wnll, off);
        wsum += __shfl_xor(wsum, off);
        bsum += __shfl_xor(bsum, off);
        dsum += __shfl_xor(dsum, off);
    }
    if (t == 0){
        float tc = wnll / wsum;
        float tm = bsum / ((float)MG * (float)HWPX);
        float td = dsum / (float)MG;
        atomicAdd(&out[0], 0.5f * tc);
        atomicAdd(&out[1], 0.5f * tm);
        atomicAdd(&out[2], 0.5f * td);
        atomicAdd(&out[3], 0.5f * (2.0f * tc + 5.0f * tm + 5.0f * td));
    }
}

extern "C" void kernel_launch(void* const* d_in, const int* in_sizes, int n_in,
                              void* d_out, int out_size, void* d_ws, size_t ws_size,
                              hipStream_t stream){
    const float* cls_logits  = (const float*)d_in[0];
    const float* mask_logits = (const float*)d_in[1];
    const int*   gt_classes  = (const int*)d_in[2];
    const int*   gt_masks    = (const int*)d_in[3];
    float* out = (float*)d_out;
    char* ws = (char*)d_ws;

    u32*   packed = (u32*)  (ws + OFF_PACKED);
    float* Ppart  = (float*)(ws + OFF_P);
    float* Plq    = (float*)(ws + OFF_PLQ);
    float* Xg     = (float*)(ws + OFF_X);
    float* Sg     = (float*)(ws + OFF_S);
    float* lqs    = (float*)(ws + OFF_LQS);

    hipLaunchKernelGGL(k_pack,   dim3(BS * HWPX / 1024),     dim3(256), 0, stream, gt_masks, packed, Xg, out);
    hipLaunchKernelGGL(k_main,   dim3(BS * NCH),             dim3(256), 0, stream, mask_logits, packed, Ppart, Plq);
    hipLaunchKernelGGL(k_reduce, dim3(BS * NTL * RED_SUB),   dim3(256), 0, stream, Ppart, Plq, Xg, Sg, lqs);
    hipLaunchKernelGGL(k_match,  dim3(BS),                   dim3(64),  0, stream, cls_logits, gt_classes, Xg, Sg, lqs, out);
}